// Round 8
// baseline (2677.641 us; speedup 1.0000x reference)
//
#include <hip/hip_runtime.h>
#include <cstdint>
#include <cstddef>

#define Bsz 2048
#define Tseq 60
#define Fin 89
#define Hd 1024
#define G4 4096
#define KX 96
#define NOUT 30
#define NBLK 512  // 16 x 32 blocks = exactly 2 blocks/CU on 256 CUs

typedef _Float16 half8 __attribute__((ext_vector_type(8)));
typedef float f32x4 __attribute__((ext_vector_type(4)));

template <int N> struct IC { static constexpr int value = N; };

__device__ __forceinline__ void gload_lds16(const void* g, void* l) {
  __builtin_amdgcn_global_load_lds((const __attribute__((address_space(1))) void*)g,
                                   (__attribute__((address_space(3))) void*)l,
                                   16, 0, 0);
}

__device__ __forceinline__ float sigmoidf_fast(float x) {
  return 1.0f / (1.0f + __expf(-x));
}

// Grid barrier, CDNA4 cross-XCD pattern:
//   per-wave s_waitcnt 0      -> this wave's h stores are in L2
//   __syncthreads             -> all waves of the block done
//   fetch_add RELEASE/agent   -> buffer_wbl2 sc1: dirty L2 -> coherent point
//   relaxed spin              -> no per-poll invalidate
//   one ACQUIRE load /agent   -> buffer_inv sc1: L1+L2 invalidated once;
//                                subsequent cached loads refetch from L3
//                                (same cost a kernel-launch boundary pays)
__device__ __forceinline__ void grid_barrier(unsigned int* bar,
                                             unsigned int target) {
  __builtin_amdgcn_s_waitcnt(0);
  __syncthreads();
  if (threadIdx.x == 0) {
    __hip_atomic_fetch_add(bar, 1u, __ATOMIC_RELEASE, __HIP_MEMORY_SCOPE_AGENT);
    unsigned int guard = 0;
    while (__hip_atomic_load(bar, __ATOMIC_RELAXED,
                             __HIP_MEMORY_SCOPE_AGENT) < target) {
      __builtin_amdgcn_s_sleep(2);
      if (++guard > (1u << 20)) break;  // safety valve: never hang the bench
    }
    (void)__hip_atomic_load(bar, __ATOMIC_ACQUIRE, __HIP_MEMORY_SCOPE_AGENT);
  }
  __syncthreads();
}

// ---------------------------------------------------------------------------
// Prep kernels (run once per launch; ws is re-poisoned before every call)
// ---------------------------------------------------------------------------

__global__ __launch_bounds__(64) void zero_bar(unsigned int* bar) {
  if (threadIdx.x == 0) *bar = 0u;
}

// x [B][T][Fin] fp32 -> xp [T][B][KX] fp16, zero-padded k in [Fin, KX)
__global__ __launch_bounds__(256) void convert_x(const float* __restrict__ x,
                                                 _Float16* __restrict__ xp) {
  int idx = blockIdx.x * 256 + threadIdx.x;   // < Tseq*Bsz*KX
  int k = idx % KX;
  int b = (idx / KX) % Bsz;
  int t = idx / (KX * Bsz);
  float v = (k < Fin) ? x[((size_t)b * Tseq + t) * Fin + k] : 0.0f;
  xp[idx] = (_Float16)v;
}

// W [Fin][G4] fp32 -> Wpt [G4][KX] fp16 (B^T layout, zero rows k>=Fin)
__global__ __launch_bounds__(256) void transpose_W(const float* __restrict__ W,
                                                   _Float16* __restrict__ Wpt) {
  __shared__ float tile[32][33];
  int n0 = blockIdx.x * 32;
  int k0 = blockIdx.y * 32;
  int tx = threadIdx.x, ty = threadIdx.y;
  for (int i = ty; i < 32; i += 8) {
    int k = k0 + i;
    tile[i][tx] = (k < Fin) ? W[(size_t)k * G4 + n0 + tx] : 0.0f;
  }
  __syncthreads();
  for (int i = ty; i < 32; i += 8)
    Wpt[(size_t)(n0 + i) * KX + k0 + tx] = (_Float16)tile[tx][i];
}

// U [Hd][G4] fp32 -> Upt [G4][Hd] fp16 (B^T layout)
__global__ __launch_bounds__(256) void transpose_U(const float* __restrict__ U,
                                                   _Float16* __restrict__ Upt) {
  __shared__ float tile[32][33];
  int n0 = blockIdx.x * 32;
  int k0 = blockIdx.y * 32;
  int tx = threadIdx.x, ty = threadIdx.y;
  for (int i = ty; i < 32; i += 8)
    tile[i][tx] = U[(size_t)(k0 + i) * G4 + n0 + tx];
  __syncthreads();
  for (int i = ty; i < 32; i += 8)
    Upt[(size_t)(n0 + i) * Hd + k0 + tx] = (_Float16)tile[tx][i];
}

// ---------------------------------------------------------------------------
// Persistent LSTM: R4's exact per-step structure (measured best, 26 us/step)
// inside one plain-launched kernel, with launch boundaries replaced by the
// release/acquire grid barrier. Deltas vs the 60-launch version:
//   - 59 launch gaps + ramp/drain boundaries removed
//   - c state in registers for all 60 steps (no 16.8 MB/step round-trip)
//   - bias + addressing hoisted out of the time loop
//   - x@W (h-independent) runs BEFORE the barrier -> absorbs arrival skew
//   - t=0 h@U skipped (h_0 = 0)
// Tiling (unchanged from R4): block = 128 rows x [4 gates x 32 units];
// XOR-swizzled LDS units (conflict-free ds_read_b128 + dense staging);
// rounds: one K=96 x@W + 16x BK=64 h@U.
// ---------------------------------------------------------------------------
__global__ __launch_bounds__(256, 2) void lstm_persist(
    const _Float16* __restrict__ xp,    // [Tseq][Bsz][KX]
    const _Float16* __restrict__ Wpt,   // [G4][KX]   (B^T)
    const _Float16* __restrict__ Upt,   // [G4][Hd]   (B^T)
    const float*    __restrict__ bias,  // [G4]
    _Float16*       __restrict__ hb0,   // [Bsz][Hd]
    _Float16*       __restrict__ hb1,   // [Bsz][Hd]
    unsigned int*   __restrict__ bar)
{
  __shared__ __align__(16) _Float16 As[3 * 4096];  // 3 subtiles x 8 units
  __shared__ __align__(16) _Float16 Bs[3 * 4096];

  const int tid  = threadIdx.x;
  const int wave = tid >> 6;
  const int lane = tid & 63;
  const int quad = lane >> 4;
  const int l16  = lane & 15;
  const int m0 = blockIdx.x * 128;   // batch-row base (fast dim, as in R4)
  const int j0 = blockIdx.y * 32;    // hidden-unit base

  const int srow = lane >> 2;                      // staging row in unit
  const int qg   = (lane & 3) ^ ((lane >> 3) & 3); // staging global chunk
  const int sA   = quad ^ ((l16 >> 1) & 3);        // fragment LDS slot

  const int hb    = 16 * (wave & 1);
  const int mwave = 64 * (wave >> 1);
  const int j  = j0 + hb + l16;
  const int uA = 4 * (wave >> 1);     // A fragment unit base (+mi)
  const int uB = wave & 1;            // B fragment unit base (2p + uB)
  const int aoff = l16 * 32 + sA * 8; // fragment offset within unit (halfs)

  float bv[4];
#pragma unroll
  for (int p = 0; p < 4; ++p) bv[p] = bias[p * Hd + j];

  // c state in registers for the whole sequence
  float cr[4][4];
#pragma unroll
  for (int mi = 0; mi < 4; ++mi)
#pragma unroll
    for (int r = 0; r < 4; ++r) cr[mi][r] = 0.0f;

  f32x4 acc[4][4];

  // stage NC 32-k subtiles of A and B, then 16*NC MFMA
  auto round = [&](auto ncI, const _Float16* __restrict__ Ab, int strA,
                   const _Float16* __restrict__ Bb, int strB, int k0) {
    constexpr int NC = decltype(ncI)::value;
    __syncthreads();  // previous round's ds_reads done before overwrite
#pragma unroll
    for (int ii = 0; ii < NC * 2; ++ii) {
      int i = ii * 4 + wave;        // 0 .. NC*8-1
      int st = i >> 3, ci = i & 7;
      gload_lds16(Ab + (size_t)(m0 + ci * 16 + srow) * strA + k0 + st * 32 + qg * 8,
                  &As[st * 4096 + ci * 512]);
    }
#pragma unroll
    for (int ii = 0; ii < NC * 2; ++ii) {
      int i = ii * 4 + wave;
      int st = i >> 3, ci = i & 7;
      int ln = ci * 16 + srow;
      int gn = (ln >> 5) * Hd + j0 + (ln & 31);   // gate-major B rows
      gload_lds16(Bb + (size_t)gn * strB + k0 + st * 32 + qg * 8,
                  &Bs[st * 4096 + ci * 512]);
    }
    __syncthreads();  // drains vmcnt(0): tiles landed
#pragma unroll
    for (int st = 0; st < NC; ++st) {
      half8 a[4], bq[4];
      for (int mi = 0; mi < 4; ++mi)
        a[mi] = *(const half8*)&As[st * 4096 + (uA + mi) * 512 + aoff];
      for (int p = 0; p < 4; ++p)
        bq[p] = *(const half8*)&Bs[st * 4096 + (2 * p + uB) * 512 + aoff];
      for (int mi = 0; mi < 4; ++mi)
        for (int p = 0; p < 4; ++p)
          acc[mi][p] = __builtin_amdgcn_mfma_f32_16x16x32_f16(a[mi], bq[p],
                                                              acc[mi][p],
                                                              0, 0, 0);
    }
  };

  for (int t = 0; t < Tseq; ++t) {
    // init acc with per-gate bias
#pragma unroll
    for (int mi = 0; mi < 4; ++mi)
#pragma unroll
      for (int p = 0; p < 4; ++p)
        acc[mi][p] = f32x4{bv[p], bv[p], bv[p], bv[p]};

    // x_t @ W : independent of h -> before the barrier (absorbs skew)
    round(IC<3>{}, xp + (size_t)t * (Bsz * KX), KX, Wpt, KX, 0);

    if (t > 0) {
      grid_barrier(bar, (unsigned int)t * NBLK);  // h_{t-1} globally visible
      const _Float16* hprev = ((t - 1) & 1) ? hb1 : hb0;
      for (int r = 0; r < 16; ++r)
        round(IC<2>{}, hprev, Hd, Upt, Hd, r * 64);
    }
    // (t == 0: h_0 = 0, entire h@U contributes nothing -- skipped)

    // gates: lane holds i,f,g,o for hidden unit j, rows quad*4+r (m89 layout)
    _Float16* hout = (t & 1) ? hb1 : hb0;
#pragma unroll
    for (int mi = 0; mi < 4; ++mi) {
#pragma unroll
      for (int r = 0; r < 4; ++r) {
        int row = m0 + mwave + mi * 16 + quad * 4 + r;
        float iv = sigmoidf_fast(acc[mi][0][r]);
        float fv = sigmoidf_fast(acc[mi][1][r]);
        float gv = fmaxf(acc[mi][2][r], 0.0f);   // relu candidate
        float ov = sigmoidf_fast(acc[mi][3][r]);
        float cv = fv * cr[mi][r] + iv * gv;
        cr[mi][r] = cv;
        float hv = ov * fmaxf(cv, 0.0f);         // relu on cell output
        hout[(size_t)row * Hd + j] = (_Float16)hv;
      }
    }
  }
}

// ---------------------------------------------------------------------------
// y[b][o] = bd[o] + sum_k h[b][k] * Wd[k][o]
// ---------------------------------------------------------------------------
__global__ __launch_bounds__(256) void final_dense(const _Float16* __restrict__ h,
                                                   const float* __restrict__ Wd,
                                                   const float* __restrict__ bd,
                                                   float* __restrict__ y) {
  __shared__ float hs[Hd];
  __shared__ float red[8][32];
  int bi = blockIdx.x;
  for (int k = threadIdx.x; k < Hd; k += 256)
    hs[k] = (float)h[(size_t)bi * Hd + k];
  __syncthreads();
  int o  = threadIdx.x & 31;
  int ch = threadIdx.x >> 5;
  float p = 0.0f;
  if (o < NOUT) {
    int k0 = ch * (Hd / 8);
    for (int k = k0; k < k0 + (Hd / 8); ++k)
      p += hs[k] * Wd[(size_t)k * NOUT + o];
  }
  red[ch][o] = p;
  __syncthreads();
  if (threadIdx.x < NOUT) {
    float s = bd[threadIdx.x];
    for (int c2 = 0; c2 < 8; ++c2) s += red[c2][threadIdx.x];
    y[(size_t)bi * NOUT + threadIdx.x] = s;
  }
}

// ---------------------------------------------------------------------------

extern "C" void kernel_launch(void* const* d_in, const int* in_sizes, int n_in,
                              void* d_out, int out_size, void* d_ws, size_t ws_size,
                              hipStream_t stream) {
  const float* x  = (const float*)d_in[0];
  const float* W  = (const float*)d_in[1];
  const float* U  = (const float*)d_in[2];
  const float* b  = (const float*)d_in[3];
  const float* Wd = (const float*)d_in[4];
  const float* bd = (const float*)d_in[5];
  float* y = (float*)d_out;

  char* ws = (char*)d_ws;
  _Float16* xp  = (_Float16*)ws; ws += (size_t)Tseq * Bsz * KX * 2;  // 23.6 MB
  _Float16* Wpt = (_Float16*)ws; ws += (size_t)G4 * KX * 2;          // 0.79 MB
  _Float16* Upt = (_Float16*)ws; ws += (size_t)G4 * Hd * 2;          // 8.4 MB
  _Float16* hb0 = (_Float16*)ws; ws += (size_t)Bsz * Hd * 2;         // 4.2 MB
  _Float16* hb1 = (_Float16*)ws; ws += (size_t)Bsz * Hd * 2;         // 4.2 MB
  unsigned int* bar = (unsigned int*)ws; ws += 256;

  zero_bar<<<1, 64, 0, stream>>>(bar);
  convert_x<<<(Tseq * Bsz * KX) / 256, 256, 0, stream>>>(x, xp);
  transpose_W<<<dim3(G4 / 32, KX / 32), dim3(32, 8), 0, stream>>>(W, Wpt);
  transpose_U<<<dim3(G4 / 32, Hd / 32), dim3(32, 8), 0, stream>>>(U, Upt);

  lstm_persist<<<dim3(Bsz / 128, G4 / 128), 256, 0, stream>>>(
      xp, Wpt, Upt, b, hb0, hb1, bar);

  // h_{59} is in hb1 (59 & 1 == 1)
  final_dense<<<Bsz, 256, 0, stream>>>(hb1, Wd, bd, y);
}

// Round 9
// 2124.784 us; speedup vs baseline: 1.2602x; 1.2602x over previous
//
#include <hip/hip_runtime.h>
#include <cstdint>
#include <cstddef>

#define Bsz 2048
#define Tseq 60
#define Fin 89
#define Hd 1024
#define G4 4096
#define KX 96
#define NOUT 30

typedef _Float16 half8 __attribute__((ext_vector_type(8)));
typedef float f32x4 __attribute__((ext_vector_type(4)));

template <int N> struct IC { static constexpr int value = N; };

__device__ __forceinline__ void gload_lds16(const void* g, void* l) {
  __builtin_amdgcn_global_load_lds((const __attribute__((address_space(1))) void*)g,
                                   (__attribute__((address_space(3))) void*)l,
                                   16, 0, 0);
}

__device__ __forceinline__ float sigmoidf_fast(float x) {
  return 1.0f / (1.0f + __expf(-x));
}

// ---------------------------------------------------------------------------
// Prep kernels (run once per launch; ws is re-poisoned before every call)
// ---------------------------------------------------------------------------

// x [B][T][Fin] fp32 -> xp [T][B][KX] fp16, zero-padded k in [Fin, KX)
__global__ __launch_bounds__(256) void convert_x(const float* __restrict__ x,
                                                 _Float16* __restrict__ xp) {
  int idx = blockIdx.x * 256 + threadIdx.x;   // < Tseq*Bsz*KX
  int k = idx % KX;
  int b = (idx / KX) % Bsz;
  int t = idx / (KX * Bsz);
  float v = (k < Fin) ? x[((size_t)b * Tseq + t) * Fin + k] : 0.0f;
  xp[idx] = (_Float16)v;
}

// W [Fin][G4] fp32 -> Wpt [G4][KX] fp16 (B^T layout, zero rows k>=Fin)
__global__ __launch_bounds__(256) void transpose_W(const float* __restrict__ W,
                                                   _Float16* __restrict__ Wpt) {
  __shared__ float tile[32][33];
  int n0 = blockIdx.x * 32;
  int k0 = blockIdx.y * 32;
  int tx = threadIdx.x, ty = threadIdx.y;
  for (int i = ty; i < 32; i += 8) {
    int k = k0 + i;
    tile[i][tx] = (k < Fin) ? W[(size_t)k * G4 + n0 + tx] : 0.0f;
  }
  __syncthreads();
  for (int i = ty; i < 32; i += 8)
    Wpt[(size_t)(n0 + i) * KX + k0 + tx] = (_Float16)tile[tx][i];
}

// U [Hd][G4] fp32 -> Upt [G4][Hd] fp16 (B^T layout)
__global__ __launch_bounds__(256) void transpose_U(const float* __restrict__ U,
                                                   _Float16* __restrict__ Upt) {
  __shared__ float tile[32][33];
  int n0 = blockIdx.x * 32;
  int k0 = blockIdx.y * 32;
  int tx = threadIdx.x, ty = threadIdx.y;
  for (int i = ty; i < 32; i += 8)
    tile[i][tx] = U[(size_t)(k0 + i) * G4 + n0 + tx];
  __syncthreads();
  for (int i = ty; i < 32; i += 8)
    Upt[(size_t)(n0 + i) * Hd + k0 + tx] = (_Float16)tile[tx][i];
}

// ---------------------------------------------------------------------------
// One LSTM step (launched 60x; launch boundary = cross-XCD coherence).
// R4's arithmetic (same 32 FLOP per LDS byte, same accumulation order, same
// register-only gate epilogue) re-cut into FINER CONCURRENCY QUANTA:
//   - 128-thread blocks, tile = 128 batch rows x [4 gates x 16 units]
//   - wave w (of 2): rows 64w..+63 (M=4 m-frags) x all 4 gates (N=4 n-frags)
//     -> FLOP/LDS-byte = 16*M*N/(M+N) = 32, the register-budget optimum
//   - grid 64 x 16 = 1024 blocks; LDS 36 KB/block caps residency at exactly
//     4 blocks/CU (8 waves/CU, same as R4) BUT in 4 independent 2-wave
//     barrier domains: each staging drain stalls 1/4 of the CU (vs 1/2),
//     with 3 other blocks to overlap it.
// LDS: 16-row units of 32 halfs, 16B chunks XOR-swizzled (slot s of row r
// holds chunk s^((r>>1)&3)) -> dense 64B staging lines, conflict-free
// ds_read_b128 (uniform 2/bank, free per m136).
// Rounds: one K=96 x@W + 16x BK=64 h@U (R4's measured-best quanta).
// ---------------------------------------------------------------------------
__global__ __launch_bounds__(128, 2) void lstm_step(
    const _Float16* __restrict__ xp_t,  // [Bsz][KX]  (this timestep)
    const _Float16* __restrict__ Wpt,   // [G4][KX]   (B^T)
    const _Float16* __restrict__ Upt,   // [G4][Hd]   (B^T)
    const float*    __restrict__ bias,  // [G4]
    const _Float16* __restrict__ h_in,  // [Bsz][Hd]
    _Float16*       __restrict__ h_out, // [Bsz][Hd]
    float*          __restrict__ cst,   // [Bsz][Hd]
    int skip_h)                          // t==0: skip h@U, c_prev = 0
{
  __shared__ __align__(16) _Float16 As[3 * 4096];  // 3 subtiles x 8 units, 24 KB
  __shared__ __align__(16) _Float16 Bs[3 * 2048];  // 3 subtiles x 4 units, 12 KB

  const int tid  = threadIdx.x;
  const int wave = tid >> 6;          // 0..1
  const int lane = tid & 63;
  const int quad = lane >> 4;
  const int l16  = lane & 15;
  const int j0 = blockIdx.x * 16;     // hidden-unit base (fast dim)
  const int m0 = blockIdx.y * 128;    // batch-row base

  const int srow = lane >> 2;                      // staging row in unit
  const int qg   = (lane & 3) ^ ((lane >> 3) & 3); // staging global chunk
  const int sA   = quad ^ ((l16 >> 1) & 3);        // fragment LDS slot

  const int j    = j0 + l16;          // this lane's hidden unit (all 4 gates)
  const int uA   = wave * 4;          // wave's A units (+mi), rows 64*wave
  const int aoff = l16 * 32 + sA * 8; // fragment offset within unit (halfs)

  float bv[4];
#pragma unroll
  for (int p = 0; p < 4; ++p) bv[p] = bias[p * Hd + j];

  f32x4 acc[4][4];
#pragma unroll
  for (int mi = 0; mi < 4; ++mi)
#pragma unroll
    for (int p = 0; p < 4; ++p)
      acc[mi][p] = f32x4{bv[p], bv[p], bv[p], bv[p]};

  // stage NC 32-k subtiles of A[128][32] + B[64][32], then 16*NC MFMA/wave
  auto round = [&](auto ncI, const _Float16* __restrict__ Ab, int strA,
                   const _Float16* __restrict__ Bb, int strB, int k0) {
    constexpr int NC = decltype(ncI)::value;
    __syncthreads();  // previous round's ds_reads done before overwrite
#pragma unroll
    for (int ii = 0; ii < NC * 4; ++ii) {      // A: NC*8 units over 2 waves
      int i = ii * 2 + wave;
      int st = i >> 3, ci = i & 7;
      gload_lds16(Ab + (size_t)(m0 + ci * 16 + srow) * strA + k0 + st * 32 + qg * 8,
                  &As[st * 4096 + ci * 512]);
    }
#pragma unroll
    for (int ii = 0; ii < NC * 2; ++ii) {      // B: NC*4 units over 2 waves
      int i = ii * 2 + wave;
      int st = i >> 2, ci = i & 3;             // ci = gate p
      gload_lds16(Bb + (size_t)(ci * Hd + j0 + srow) * strB + k0 + st * 32 + qg * 8,
                  &Bs[st * 2048 + ci * 512]);
    }
    __syncthreads();  // drains vmcnt(0): tiles landed
#pragma unroll
    for (int st = 0; st < NC; ++st) {
      half8 a[4], bq[4];
      for (int mi = 0; mi < 4; ++mi)
        a[mi] = *(const half8*)&As[st * 4096 + (uA + mi) * 512 + aoff];
      for (int p = 0; p < 4; ++p)
        bq[p] = *(const half8*)&Bs[st * 2048 + p * 512 + aoff];
      for (int mi = 0; mi < 4; ++mi)
        for (int p = 0; p < 4; ++p)
          acc[mi][p] = __builtin_amdgcn_mfma_f32_16x16x32_f16(a[mi], bq[p],
                                                              acc[mi][p],
                                                              0, 0, 0);
    }
  };

  // x_t @ W : K = 96 = 3 subtiles, one barrier pair
  round(IC<3>{}, xp_t, KX, Wpt, KX, 0);

  // h_{t-1} @ U : 16 rounds of BK=64 (skipped at t=0, h_0 = 0)
  if (!skip_h) {
    for (int r = 0; r < 16; ++r)
      round(IC<2>{}, h_in, Hd, Upt, Hd, r * 64);
  }

  // epilogue: lane holds i,f,g,o for hidden unit j, rows quad*4+r (m89 layout)
#pragma unroll
  for (int mi = 0; mi < 4; ++mi) {
#pragma unroll
    for (int r = 0; r < 4; ++r) {
      int row = m0 + wave * 64 + mi * 16 + quad * 4 + r;
      size_t idx = (size_t)row * Hd + j;
      float iv = sigmoidf_fast(acc[mi][0][r]);
      float fv = sigmoidf_fast(acc[mi][1][r]);
      float gv = fmaxf(acc[mi][2][r], 0.0f);   // relu candidate
      float ov = sigmoidf_fast(acc[mi][3][r]);
      float cprev = skip_h ? 0.0f : cst[idx];  // c_0 = 0 folded in
      float cv = fv * cprev + iv * gv;
      cst[idx] = cv;
      float hv = ov * fmaxf(cv, 0.0f);         // relu on cell output
      h_out[idx] = (_Float16)hv;
    }
  }
}

// ---------------------------------------------------------------------------
// y[b][o] = bd[o] + sum_k h[b][k] * Wd[k][o]
// ---------------------------------------------------------------------------
__global__ __launch_bounds__(256) void final_dense(const _Float16* __restrict__ h,
                                                   const float* __restrict__ Wd,
                                                   const float* __restrict__ bd,
                                                   float* __restrict__ y) {
  __shared__ float hs[Hd];
  __shared__ float red[8][32];
  int bi = blockIdx.x;
  for (int k = threadIdx.x; k < Hd; k += 256)
    hs[k] = (float)h[(size_t)bi * Hd + k];
  __syncthreads();
  int o  = threadIdx.x & 31;
  int ch = threadIdx.x >> 5;
  float p = 0.0f;
  if (o < NOUT) {
    int k0 = ch * (Hd / 8);
    for (int k = k0; k < k0 + (Hd / 8); ++k)
      p += hs[k] * Wd[(size_t)k * NOUT + o];
  }
  red[ch][o] = p;
  __syncthreads();
  if (threadIdx.x < NOUT) {
    float s = bd[threadIdx.x];
    for (int c2 = 0; c2 < 8; ++c2) s += red[c2][threadIdx.x];
    y[(size_t)bi * NOUT + threadIdx.x] = s;
  }
}

// ---------------------------------------------------------------------------

extern "C" void kernel_launch(void* const* d_in, const int* in_sizes, int n_in,
                              void* d_out, int out_size, void* d_ws, size_t ws_size,
                              hipStream_t stream) {
  const float* x  = (const float*)d_in[0];
  const float* W  = (const float*)d_in[1];
  const float* U  = (const float*)d_in[2];
  const float* b  = (const float*)d_in[3];
  const float* Wd = (const float*)d_in[4];
  const float* bd = (const float*)d_in[5];
  float* y = (float*)d_out;

  char* ws = (char*)d_ws;
  _Float16* xp  = (_Float16*)ws; ws += (size_t)Tseq * Bsz * KX * 2;  // 23.6 MB
  _Float16* Wpt = (_Float16*)ws; ws += (size_t)G4 * KX * 2;          // 0.79 MB
  _Float16* Upt = (_Float16*)ws; ws += (size_t)G4 * Hd * 2;          // 8.4 MB
  _Float16* hb0 = (_Float16*)ws; ws += (size_t)Bsz * Hd * 2;         // 4.2 MB
  _Float16* hb1 = (_Float16*)ws; ws += (size_t)Bsz * Hd * 2;         // 4.2 MB
  float*    cst = (float*)ws;    ws += (size_t)Bsz * Hd * 4;         // 8.4 MB

  convert_x<<<(Tseq * Bsz * KX) / 256, 256, 0, stream>>>(x, xp);
  transpose_W<<<dim3(G4 / 32, KX / 32), dim3(32, 8), 0, stream>>>(W, Wpt);
  transpose_U<<<dim3(G4 / 32, Hd / 32), dim3(32, 8), 0, stream>>>(U, Upt);

  for (int t = 0; t < Tseq; ++t) {
    const _Float16* hin  = ((t - 1) & 1) ? hb1 : hb0;   // unused at t=0
    _Float16*       hout = (t & 1) ? hb1 : hb0;
    // grid: 64 j-blocks (16 units each) fast, 16 m-blocks slow; 128 thr
    lstm_step<<<dim3(Hd / 16, Bsz / 128), 128, 0, stream>>>(
        xp + (size_t)t * (Bsz * KX), Wpt, Upt, b,
        (t == 0) ? hb0 : hin, hout, cst, (t == 0) ? 1 : 0);
  }

  // h_{59} is in hb1 (59 & 1 == 1)
  final_dense<<<Bsz, 256, 0, stream>>>(hb1, Wd, bd, y);
}